// Round 6
// baseline (384.008 us; speedup 1.0000x reference)
//
#include <hip/hip_runtime.h>

typedef __bf16 bf16;
typedef __bf16 bf16x8 __attribute__((ext_vector_type(8)));
typedef float f32x4 __attribute__((ext_vector_type(4)));

#define NN 8192

// k-slot permutation (verified R4-correct pair): fragment position p = lg*8+j holds
// k(p) = (p>>3)*4 + (p&3) + ((p&4)?16:0). A loads are dense 128B/row; B packed inverse.
__device__ inline int pinv32(int k) {
  return ((k >> 2) & 3) * 8 + (k & 3) + ((k & 16) ? 4 : 0);
}

__device__ inline bf16x8 cvt8(float4 lo, float4 hi) {
  bf16x8 r;
  r[0] = (__bf16)lo.x; r[1] = (__bf16)lo.y; r[2] = (__bf16)lo.z; r[3] = (__bf16)lo.w;
  r[4] = (__bf16)hi.x; r[5] = (__bf16)hi.y; r[6] = (__bf16)hi.z; r[7] = (__bf16)hi.w;
  return r;
}

// ---------------- enc1: B1p[ktile][c(128)][p] = relu(nodes @ We1 + be1), k-permuted pack
__global__ __launch_bounds__(256) void k_enc1(const float* __restrict__ nodes,
                                              const float* __restrict__ We1,
                                              const float* __restrict__ be1,
                                              bf16* __restrict__ B1p) {
  __shared__ float Ns[32 * 68];
  __shared__ bf16 Os[128 * 40];
  int tid = threadIdx.x;
  int r0 = blockIdx.x * 32;
  for (int idx = tid; idx < 512; idx += 256) {
    int r = idx >> 4, c4 = (idx & 15) * 4;
    *(float4*)(&Ns[r * 68 + c4]) = *(const float4*)(nodes + (r0 + r) * 64 + c4);
  }
  __syncthreads();
  int c = tid & 127, rb = tid >> 7;  // rows rb + 2k, k<16
  float acc[16];
  float b = be1[c];
#pragma unroll
  for (int k = 0; k < 16; ++k) acc[k] = b;
  for (int f = 0; f < 64; ++f) {
    float wv = We1[f * 128 + c];
#pragma unroll
    for (int k = 0; k < 16; ++k)
      acc[k] = fmaf(Ns[(rb + 2 * k) * 68 + f], wv, acc[k]);
  }
#pragma unroll
  for (int k = 0; k < 16; ++k) {
    float v = acc[k] > 0.f ? acc[k] : 0.f;
    Os[c * 40 + pinv32(rb + 2 * k)] = (bf16)v;
  }
  __syncthreads();
  int c2 = tid >> 1, h = tid & 1;
  const uint4* src = (const uint4*)(Os + c2 * 40 + h * 16);
  uint4* dst = (uint4*)(B1p + (size_t)blockIdx.x * 128 * 32 + c2 * 32 + h * 16);
  dst[0] = src[0]; dst[1] = src[1];
}

// ---------------- pass: Out[r][c] = A @ Bpacked, FULL K per wave.
// 512 blocks x 16 rows (contiguous 512KB A-slab streamed front-to-back).
// 4 waves share the rows, each owns NCG*16 cols. A prefetched 8 substeps (256 k)
// ahead in registers; B 2 substeps ahead. No LDS, no barriers, no k-partials.
template <int NCG>
__global__ __launch_bounds__(256, 2) void k_pass(const float* __restrict__ A,
                                                 const bf16* __restrict__ Bp,
                                                 float* __restrict__ Out) {
  constexpr int COLS = NCG * 64;
  int tid = threadIdx.x;
  int lane = tid & 63, w = tid >> 6;
  int l15 = lane & 15, lg = lane >> 4;
  int r0 = blockIdx.x * 16;
  int wc0 = w * (NCG * 16);
  const float* pa = A + (size_t)(r0 + l15) * NN + lg * 4;
  const bf16* pb = Bp + (size_t)(wc0 + l15) * 32 + lg * 8;

  f32x4 acc[NCG];
#pragma unroll
  for (int nf = 0; nf < NCG; ++nf) acc[nf] = (f32x4){0.f, 0.f, 0.f, 0.f};

  float4 a[8][2];
  uint4 b[2][NCG];

  auto LDA = [&](int k, float4* s) {
    s[0] = *(const float4*)(pa + k);
    s[1] = *(const float4*)(pa + k + 16);
  };
  auto LDB = [&](int k, uint4* bb) {
    const bf16* p = pb + (size_t)(k >> 5) * (COLS * 32);
#pragma unroll
    for (int nf = 0; nf < NCG; ++nf) bb[nf] = *(const uint4*)(p + nf * 512);
  };
  auto CMP = [&](const float4* s, const uint4* bb) {
    bf16x8 afr = cvt8(s[0], s[1]);
#pragma unroll
    for (int nf = 0; nf < NCG; ++nf)
      acc[nf] = __builtin_amdgcn_mfma_f32_16x16x32_bf16(
          afr, __builtin_bit_cast(bf16x8, bb[nf]), acc[nf], 0, 0, 0);
  };

  // prologue: A slots k=0..224, B slots k=0,32
#pragma unroll
  for (int j = 0; j < 8; ++j) LDA(j * 32, a[j]);
  LDB(0, b[0]);
  LDB(32, b[1]);

  for (int kt = 0; kt <= NN - 512; kt += 256) {
#pragma unroll
    for (int j = 0; j < 8; ++j) {
      int k = kt + j * 32;
      CMP(a[j], b[j & 1]);
      LDA(k + 256, a[j]);
      LDB(k + 64, b[j & 1]);
    }
  }
  // epilogue: kt = NN-256, all A preloaded; B guarded
#pragma unroll
  for (int j = 0; j < 8; ++j) {
    int k = (NN - 256) + j * 32;
    CMP(a[j], b[j & 1]);
    if (j < 6) LDB(k + 64, b[j & 1]);
  }

#pragma unroll
  for (int nf = 0; nf < NCG; ++nf)
#pragma unroll
    for (int i = 0; i < 4; ++i)
      Out[(size_t)(r0 + lg * 4 + i) * COLS + wc0 + nf * 16 + l15] = acc[nf][i];
}

// ---------------- mid: B3p[ktile][c(64)][p] = relu(X2 @ We2 + be2), k-permuted pack
__global__ __launch_bounds__(256) void k_mid(const float* __restrict__ X2,
                                             const float* __restrict__ We2,
                                             const float* __restrict__ be2,
                                             bf16* __restrict__ B3p) {
  __shared__ float X2s[32 * 128];
  __shared__ bf16 Os[64 * 40];
  int tid = threadIdx.x;
  int r0 = blockIdx.x * 32;
  for (int idx = tid; idx < 1024; idx += 256) {
    int r = idx >> 5, c4 = (idx & 31) * 4;
    *(float4*)(&X2s[r * 128 + c4]) = *(const float4*)(X2 + (size_t)(r0 + r) * 128 + c4);
  }
  __syncthreads();
  int c = tid & 63, rb = tid >> 6;  // rows rb + 4k, k<8
  float acc[8];
  float b = be2[c];
#pragma unroll
  for (int k = 0; k < 8; ++k) acc[k] = b;
  for (int j = 0; j < 128; ++j) {
    float wv = We2[j * 64 + c];
#pragma unroll
    for (int k = 0; k < 8; ++k)
      acc[k] = fmaf(X2s[(rb + 4 * k) * 128 + j], wv, acc[k]);
  }
#pragma unroll
  for (int k = 0; k < 8; ++k) {
    float v = acc[k] > 0.f ? acc[k] : 0.f;
    Os[c * 40 + pinv32(rb + 4 * k)] = (bf16)v;
  }
  __syncthreads();
  int c2 = tid >> 2, h = tid & 3;
  const uint4* src = (const uint4*)(Os + c2 * 40 + h * 8);
  uint4* dst = (uint4*)(B3p + (size_t)blockIdx.x * 64 * 32 + c2 * 32 + h * 8);
  dst[0] = src[0];
}

// ---------------- head
__global__ __launch_bounds__(256) void k_head(const float* __restrict__ X4,
                                              const float* __restrict__ actions,
                                              const float* __restrict__ Weo,
                                              const float* __restrict__ beo,
                                              const float* __restrict__ Wc1,
                                              const float* __restrict__ bc1,
                                              const float* __restrict__ Wc2,
                                              const float* __restrict__ bc2,
                                              const float* __restrict__ Wq,
                                              const float* __restrict__ bq,
                                              float* __restrict__ q) {
  __shared__ float X4s[32 * 65];
  __shared__ float hs[32 * 81];
  __shared__ float h1s[32 * 129];
  __shared__ float h2s[32 * 65];
  int tid = threadIdx.x;
  int r0 = blockIdx.x * 32;
  for (int idx = tid; idx < 2048; idx += 256) {
    int r = idx >> 6, c = idx & 63;
    X4s[r * 65 + c] = X4[(size_t)(r0 + r) * 64 + c];
  }
  for (int idx = tid; idx < 512; idx += 256) {
    int r = idx >> 4, a = idx & 15;
    hs[r * 81 + 64 + a] = actions[(r0 + r) * 16 + a];
  }
  __syncthreads();
  {
    int c = tid & 63, rb = tid >> 6;
    float acc[8];
    float b = beo[c];
#pragma unroll
    for (int k = 0; k < 8; ++k) acc[k] = b;
    for (int j = 0; j < 64; ++j) {
      float wv = Weo[j * 64 + c];
#pragma unroll
      for (int k = 0; k < 8; ++k)
        acc[k] = fmaf(X4s[(rb + 4 * k) * 65 + j], wv, acc[k]);
    }
#pragma unroll
    for (int k = 0; k < 8; ++k) hs[(rb + 4 * k) * 81 + c] = acc[k];
  }
  __syncthreads();
  {
    int c = tid & 127, rb = tid >> 7;
    float acc[16];
    float b = bc1[c];
#pragma unroll
    for (int k = 0; k < 16; ++k) acc[k] = b;
    for (int j = 0; j < 80; ++j) {
      float wv = Wc1[j * 128 + c];
#pragma unroll
      for (int k = 0; k < 16; ++k)
        acc[k] = fmaf(hs[(rb + 2 * k) * 81 + j], wv, acc[k]);
    }
#pragma unroll
    for (int k = 0; k < 16; ++k) {
      float v = acc[k] > 0.f ? acc[k] : 0.f;
      h1s[(rb + 2 * k) * 129 + c] = v;
    }
  }
  __syncthreads();
  {
    int c = tid & 63, rb = tid >> 6;
    float acc[8];
    float b = bc2[c];
#pragma unroll
    for (int k = 0; k < 8; ++k) acc[k] = b;
    for (int j = 0; j < 128; ++j) {
      float wv = Wc2[j * 64 + c];
#pragma unroll
      for (int k = 0; k < 8; ++k)
        acc[k] = fmaf(h1s[(rb + 4 * k) * 129 + j], wv, acc[k]);
    }
#pragma unroll
    for (int k = 0; k < 8; ++k) {
      float v = acc[k] > 0.f ? acc[k] : 0.f;
      h2s[(rb + 4 * k) * 65 + c] = v;
    }
  }
  __syncthreads();
  if (tid < 32) {
    float acc = bq[0];
    for (int j = 0; j < 64; ++j) acc = fmaf(h2s[tid * 65 + j], Wq[j], acc);
    q[r0 + tid] = acc;
  }
}

extern "C" void kernel_launch(void* const* d_in, const int* in_sizes, int n_in,
                              void* d_out, int out_size, void* d_ws, size_t ws_size,
                              hipStream_t stream) {
  const float* nodes = (const float*)d_in[0];
  const float* A = (const float*)d_in[2];
  const float* actions = (const float*)d_in[3];
  const float* We1 = (const float*)d_in[4];
  const float* be1 = (const float*)d_in[5];
  const float* We2 = (const float*)d_in[6];
  const float* be2 = (const float*)d_in[7];
  const float* Weo = (const float*)d_in[8];
  const float* beo = (const float*)d_in[9];
  const float* Wc1 = (const float*)d_in[10];
  const float* bc1 = (const float*)d_in[11];
  const float* Wc2 = (const float*)d_in[12];
  const float* bc2 = (const float*)d_in[13];
  const float* Wq = (const float*)d_in[14];
  const float* bq = (const float*)d_in[15];
  float* q = (float*)d_out;

  const size_t MB = 1ull << 20;
  char* ws = (char*)d_ws;
  bf16* B1p = (bf16*)(ws);              // 2 MB [256][128][32]
  bf16* B3p = (bf16*)(ws + 2 * MB);     // 1 MB [256][64][32]
  float* X2 = (float*)(ws + 3 * MB);    // 4 MB [8192][128]
  float* X4 = (float*)(ws + 7 * MB);    // 2 MB [8192][64]

  k_enc1<<<256, 256, 0, stream>>>(nodes, We1, be1, B1p);
  k_pass<2><<<512, 256, 0, stream>>>(A, B1p, X2);
  k_mid<<<256, 256, 0, stream>>>(X2, We2, be2, B3p);
  k_pass<1><<<512, 256, 0, stream>>>(A, B3p, X4);
  k_head<<<256, 256, 0, stream>>>(X4, actions, Weo, beo, Wc1, bc1, Wc2, bc2, Wq, bq, q);
}

// Round 7
// 269.997 us; speedup vs baseline: 1.4223x; 1.4223x over previous
//
#include <hip/hip_runtime.h>

typedef __bf16 bf16;
typedef __bf16 bf16x8 __attribute__((ext_vector_type(8)));
typedef float f32x4 __attribute__((ext_vector_type(4)));

#define NN 8192

__device__ inline bf16x8 cvt8(float4 lo, float4 hi) {
  bf16x8 r;
  r[0] = (__bf16)lo.x; r[1] = (__bf16)lo.y; r[2] = (__bf16)lo.z; r[3] = (__bf16)lo.w;
  r[4] = (__bf16)hi.x; r[5] = (__bf16)hi.y; r[6] = (__bf16)hi.z; r[7] = (__bf16)hi.w;
  return r;
}

// ---------------- repack: A f32 row-major -> Apk bf16, MFMA-A-fragment packed.
// Fragment f = rt*256 + kt (16 rows x 32 k): lane l holds row rt*16+(l&15),
// k = kt*32 + (l>>4)*8 + j, stored at Apk[f*512 + l*8]. Both global sides are
// 1KB-contiguous per wave instruction (copy-like).
__global__ __launch_bounds__(256) void k_repack(const float* __restrict__ A,
                                                bf16* __restrict__ Apk) {
  __shared__ float As[16 * 516];  // stride 516: pack-read is 2-way (free)
  int tid = threadIdx.x;
  int rt = blockIdx.x;   // 512 row-tiles of 16
  int kc = blockIdx.y;   // 16 k-chunks of 512
  const float* src = A + (size_t)rt * 16 * NN + kc * 512;
#pragma unroll
  for (int i = 0; i < 8; ++i) {
    int idx = i * 256 + tid;          // float4 index in 16x512 chunk
    int r = idx >> 7;                 // 128 float4 per row
    int c4 = (idx & 127) * 4;
    float4 v = *(const float4*)(src + (size_t)r * NN + c4);
    *(float4*)(&As[r * 516 + c4]) = v;
  }
  __syncthreads();
  int lane = tid & 63, w = tid >> 6;
  int l15 = lane & 15, lg = lane >> 4;
  size_t fbase = ((size_t)rt * 256 + (size_t)kc * 16) * 512;
#pragma unroll
  for (int t = 0; t < 4; ++t) {
    int kt = w * 4 + t;
    const float* p = &As[l15 * 516 + kt * 32 + lg * 8];
    float4 lo = *(const float4*)p;
    float4 hi = *(const float4*)(p + 4);
    bf16x8 v = cvt8(lo, hi);
    *(bf16x8*)(Apk + fbase + (size_t)kt * 512 + lane * 8) = v;
  }
}

// ---------------- enc1: B1p[kt][c(128)][k&31] = relu(nodes @ We1 + be1), identity pack
__global__ __launch_bounds__(256) void k_enc1(const float* __restrict__ nodes,
                                              const float* __restrict__ We1,
                                              const float* __restrict__ be1,
                                              bf16* __restrict__ B1p) {
  __shared__ float Ns[32 * 68];
  __shared__ bf16 Os[128 * 40];
  int tid = threadIdx.x;
  int r0 = blockIdx.x * 32;
  for (int idx = tid; idx < 512; idx += 256) {
    int r = idx >> 4, c4 = (idx & 15) * 4;
    *(float4*)(&Ns[r * 68 + c4]) = *(const float4*)(nodes + (r0 + r) * 64 + c4);
  }
  __syncthreads();
  int c = tid & 127, rb = tid >> 7;  // k = rb + 2j
  float acc[16];
  float b = be1[c];
#pragma unroll
  for (int k = 0; k < 16; ++k) acc[k] = b;
  for (int f = 0; f < 64; ++f) {
    float wv = We1[f * 128 + c];
#pragma unroll
    for (int k = 0; k < 16; ++k)
      acc[k] = fmaf(Ns[(rb + 2 * k) * 68 + f], wv, acc[k]);
  }
#pragma unroll
  for (int k = 0; k < 16; ++k) {
    float v = acc[k] > 0.f ? acc[k] : 0.f;
    Os[c * 40 + rb + 2 * k] = (bf16)v;
  }
  __syncthreads();
  int c2 = tid >> 1, h = tid & 1;
  const uint4* src = (const uint4*)(Os + c2 * 40 + h * 16);
  uint4* dst = (uint4*)(B1p + (size_t)blockIdx.x * 128 * 32 + c2 * 32 + h * 16);
  dst[0] = src[0]; dst[1] = src[1];
}

// ---------------- pass: Out[z][r][c] = Apk-rows @ Bpacked. Pure register streaming.
// Block = 16 rows (one rt), 4 waves each owning TC/4 cols. A stream is contiguous
// 1KB fragments (16B/lane); zero cvt. A 8-deep, B 4-deep prefetch. KS=2 k-split.
template <int TC>
__global__ __launch_bounds__(256, 4) void k_pass(const bf16* __restrict__ Apk,
                                                 const bf16* __restrict__ Bp,
                                                 float* __restrict__ Out) {
  constexpr int NCG = TC / 64;   // col-fragments per wave
  int tid = threadIdx.x;
  int lane = tid & 63, w = tid >> 6;
  int l15 = lane & 15, lg = lane >> 4;
  int rt = blockIdx.x;
  int kz = blockIdx.y * 128;     // fragment index base (KL=4096 -> 128 kts)
  const bf16* pa = Apk + ((size_t)rt * 256 + kz) * 512 + lane * 8;
  const bf16* pb = Bp + (size_t)kz * (TC * 32) + (size_t)(w * (NCG * 16) + l15) * 32 + lg * 8;

  f32x4 acc[NCG];
#pragma unroll
  for (int nf = 0; nf < NCG; ++nf) acc[nf] = (f32x4){0.f, 0.f, 0.f, 0.f};

  uint4 a[8];
  uint4 b[4][NCG];

  auto LDA = [&](int j, int slot) { a[slot] = *(const uint4*)(pa + (size_t)j * 512); };
  auto LDB = [&](int j, int slot) {
    const bf16* p = pb + (size_t)j * (TC * 32);
#pragma unroll
    for (int nf = 0; nf < NCG; ++nf) b[slot][nf] = *(const uint4*)(p + nf * 512);
  };
  auto CMP = [&](int aslot, int bslot) {
    bf16x8 af = __builtin_bit_cast(bf16x8, a[aslot]);
#pragma unroll
    for (int nf = 0; nf < NCG; ++nf)
      acc[nf] = __builtin_amdgcn_mfma_f32_16x16x32_bf16(
          af, __builtin_bit_cast(bf16x8, b[bslot][nf]), acc[nf], 0, 0, 0);
  };

#pragma unroll
  for (int j = 0; j < 8; ++j) LDA(j, j);
#pragma unroll
  for (int j = 0; j < 4; ++j) LDB(j, j);

  for (int kt = 0; kt < 112; kt += 8) {
#pragma unroll
    for (int j = 0; j < 8; ++j) {
      CMP(j, j & 3);
      LDA(kt + j + 8, j);
      LDB(kt + j + 4, j & 3);
    }
  }
  // kt = 112..119: consume, keep B topped up (116..123 < 128)
#pragma unroll
  for (int j = 0; j < 8; ++j) {
    CMP(j, j & 3);
    LDA(112 + j + 8, j);   // loads kts 120..127
    if (j < 4) LDB(116 + j, j & 3);  // wait: see note below
  }
  // note: B slots for kts 120..127: slot (kt&3); kts 120..123 loaded above into
  // slots 0..3; load kts 124..127 now:
#pragma unroll
  for (int j = 4; j < 8; ++j) LDB(120 + j, j & 3);
  // kt = 120..127: pure consume
#pragma unroll
  for (int j = 0; j < 8; ++j) CMP(j, j & 3);

  float* out = Out + (size_t)blockIdx.y * NN * TC;
#pragma unroll
  for (int nf = 0; nf < NCG; ++nf)
#pragma unroll
    for (int i = 0; i < 4; ++i)
      out[(size_t)(rt * 16 + lg * 4 + i) * TC + w * (NCG * 16) + nf * 16 + l15] = acc[nf][i];
}

// ---------------- mid: B3p[kt][c(64)][k&31] = relu(sum_z X2p @ We2 + be2), identity pack
__global__ __launch_bounds__(256) void k_mid(const float* __restrict__ X2p,
                                             const float* __restrict__ We2,
                                             const float* __restrict__ be2,
                                             bf16* __restrict__ B3p) {
  __shared__ float X2s[32 * 128];
  __shared__ bf16 Os[64 * 40];
  int tid = threadIdx.x;
  int r0 = blockIdx.x * 32;
  for (int idx = tid; idx < 1024; idx += 256) {
    int r = idx >> 5, c4 = (idx & 31) * 4;
    float4 u = *(const float4*)(X2p + (size_t)(r0 + r) * 128 + c4);
    float4 v = *(const float4*)(X2p + (size_t)NN * 128 + (size_t)(r0 + r) * 128 + c4);
    u.x += v.x; u.y += v.y; u.z += v.z; u.w += v.w;
    *(float4*)(&X2s[r * 128 + c4]) = u;
  }
  __syncthreads();
  int c = tid & 63, rb = tid >> 6;  // k = rb + 4j
  float acc[8];
  float b = be2[c];
#pragma unroll
  for (int k = 0; k < 8; ++k) acc[k] = b;
  for (int j = 0; j < 128; ++j) {
    float wv = We2[j * 64 + c];
#pragma unroll
    for (int k = 0; k < 8; ++k)
      acc[k] = fmaf(X2s[(rb + 4 * k) * 128 + j], wv, acc[k]);
  }
#pragma unroll
  for (int k = 0; k < 8; ++k) {
    float v = acc[k] > 0.f ? acc[k] : 0.f;
    Os[c * 40 + rb + 4 * k] = (bf16)v;
  }
  __syncthreads();
  int c2 = tid >> 2, h = tid & 3;
  const uint4* src = (const uint4*)(Os + c2 * 40 + h * 8);
  uint4* dst = (uint4*)(B3p + (size_t)blockIdx.x * 64 * 32 + c2 * 32 + h * 8);
  dst[0] = src[0];
}

// ---------------- head
__global__ __launch_bounds__(256) void k_head(const float* __restrict__ X4p,
                                              const float* __restrict__ actions,
                                              const float* __restrict__ Weo,
                                              const float* __restrict__ beo,
                                              const float* __restrict__ Wc1,
                                              const float* __restrict__ bc1,
                                              const float* __restrict__ Wc2,
                                              const float* __restrict__ bc2,
                                              const float* __restrict__ Wq,
                                              const float* __restrict__ bq,
                                              float* __restrict__ q) {
  __shared__ float X4s[32 * 65];
  __shared__ float hs[32 * 81];
  __shared__ float h1s[32 * 129];
  __shared__ float h2s[32 * 65];
  int tid = threadIdx.x;
  int r0 = blockIdx.x * 32;
  for (int idx = tid; idx < 2048; idx += 256) {
    int r = idx >> 6, c = idx & 63;
    X4s[r * 65 + c] = X4p[(size_t)(r0 + r) * 64 + c] +
                      X4p[(size_t)NN * 64 + (size_t)(r0 + r) * 64 + c];
  }
  for (int idx = tid; idx < 512; idx += 256) {
    int r = idx >> 4, a = idx & 15;
    hs[r * 81 + 64 + a] = actions[(r0 + r) * 16 + a];
  }
  __syncthreads();
  {
    int c = tid & 63, rb = tid >> 6;
    float acc[8];
    float b = beo[c];
#pragma unroll
    for (int k = 0; k < 8; ++k) acc[k] = b;
    for (int j = 0; j < 64; ++j) {
      float wv = Weo[j * 64 + c];
#pragma unroll
      for (int k = 0; k < 8; ++k)
        acc[k] = fmaf(X4s[(rb + 4 * k) * 65 + j], wv, acc[k]);
    }
#pragma unroll
    for (int k = 0; k < 8; ++k) hs[(rb + 4 * k) * 81 + c] = acc[k];
  }
  __syncthreads();
  {
    int c = tid & 127, rb = tid >> 7;
    float acc[16];
    float b = bc1[c];
#pragma unroll
    for (int k = 0; k < 16; ++k) acc[k] = b;
    for (int j = 0; j < 80; ++j) {
      float wv = Wc1[j * 128 + c];
#pragma unroll
      for (int k = 0; k < 16; ++k)
        acc[k] = fmaf(hs[(rb + 2 * k) * 81 + j], wv, acc[k]);
    }
#pragma unroll
    for (int k = 0; k < 16; ++k) {
      float v = acc[k] > 0.f ? acc[k] : 0.f;
      h1s[(rb + 2 * k) * 129 + c] = v;
    }
  }
  __syncthreads();
  {
    int c = tid & 63, rb = tid >> 6;
    float acc[8];
    float b = bc2[c];
#pragma unroll
    for (int k = 0; k < 8; ++k) acc[k] = b;
    for (int j = 0; j < 128; ++j) {
      float wv = Wc2[j * 64 + c];
#pragma unroll
      for (int k = 0; k < 8; ++k)
        acc[k] = fmaf(h1s[(rb + 4 * k) * 129 + j], wv, acc[k]);
    }
#pragma unroll
    for (int k = 0; k < 8; ++k) {
      float v = acc[k] > 0.f ? acc[k] : 0.f;
      h2s[(rb + 4 * k) * 65 + c] = v;
    }
  }
  __syncthreads();
  if (tid < 32) {
    float acc = bq[0];
    for (int j = 0; j < 64; ++j) acc = fmaf(h2s[tid * 65 + j], Wq[j], acc);
    q[r0 + tid] = acc;
  }
}

extern "C" void kernel_launch(void* const* d_in, const int* in_sizes, int n_in,
                              void* d_out, int out_size, void* d_ws, size_t ws_size,
                              hipStream_t stream) {
  const float* nodes = (const float*)d_in[0];
  const float* A = (const float*)d_in[2];
  const float* actions = (const float*)d_in[3];
  const float* We1 = (const float*)d_in[4];
  const float* be1 = (const float*)d_in[5];
  const float* We2 = (const float*)d_in[6];
  const float* be2 = (const float*)d_in[7];
  const float* Weo = (const float*)d_in[8];
  const float* beo = (const float*)d_in[9];
  const float* Wc1 = (const float*)d_in[10];
  const float* bc1 = (const float*)d_in[11];
  const float* Wc2 = (const float*)d_in[12];
  const float* bc2 = (const float*)d_in[13];
  const float* Wq = (const float*)d_in[14];
  const float* bq = (const float*)d_in[15];
  float* q = (float*)d_out;

  const size_t MB = 1ull << 20;
  char* ws = (char*)d_ws;
  bf16* B1p = (bf16*)(ws);               // 2 MB  [256][128][32]
  bf16* B3p = (bf16*)(ws + 2 * MB);      // 1 MB  [256][64][32]
  float* X2p = (float*)(ws + 3 * MB);    // 8 MB  [2][8192][128]
  float* X4p = (float*)(ws + 11 * MB);   // 4 MB  [2][8192][64]
  bf16* Apk = (bf16*)(ws + 16 * MB);     // 128 MB [512*256 frags][512]

  k_repack<<<dim3(512, 16), 256, 0, stream>>>(A, Apk);
  k_enc1<<<256, 256, 0, stream>>>(nodes, We1, be1, B1p);
  k_pass<128><<<dim3(512, 2), 256, 0, stream>>>(Apk, B1p, X2p);
  k_mid<<<256, 256, 0, stream>>>(X2p, We2, be2, B3p);
  k_pass<64><<<dim3(512, 2), 256, 0, stream>>>(Apk, B3p, X4p);
  k_head<<<256, 256, 0, stream>>>(X4p, actions, Weo, beo, Wc1, bc1, Wc2, bc2, Wq, bq, q);
}